// Round 12
// baseline (20.174 us; speedup 1.0000x reference)
//
#include <hip/hip_runtime.h>

#define NUM_EMBEDDINGS 50000
#define EMBEDDING_DIM  1024
#define N_CENTROIDS    256
#define N_BLOCKS       128    // EMBEDDING_DIM / 8
#define N_TOKENS       16384  // BATCH * SEQ
#define N_PARTS        8      // one per XCD
#define BLKS_PER_PART  16     // N_BLOCKS / N_PARTS
#define TOK_PER_BLOCK  64
#define CHUNK          16     // tokens per pipeline stage (4 stages)

typedef float f32x4 __attribute__((ext_vector_type(4)));

// Software-pipelined gather: prefetch chunk i+1's codes WHILE storing chunk i.
//
// Geometry (proven pieces kept): 2048 blocks = 8/CU resident, part = bid&7
// (XCD-local 3.2 MB assignments slice in L2), nt f32x4 stores (R3->R5 +6us),
// stride-9 LDS centroid table (conflict-free for random codes).
//
// R11 showed phase A (code gather) serializes before phase B (store stream):
// ~4us + ~11us. Here each 64-token block runs a 4-stage pipeline over
// 16-token chunks:
//   ds_write codes[i]  (waits vmcnt on the chunk-i load ONLY — the prefetch
//                       for i is issued BEFORE chunk i-1's stores, so the
//                       compiler can wait vmcnt(2) without draining stores)
//   barrier
//   issue chunk-i+1 code loads (1/thread, independent -> fills the shadow)
//   store chunk i      (2 nt stores + LDS reads per thread)
//   barrier
// The scattered-gather latency/L2 service hides under the store stream.
__global__ __launch_bounds__(256) void pq_embed_pipe_kernel(
    const float* __restrict__ centroids,     // [256][8]
    const int*   __restrict__ assignments,   // [128][50000]
    const int*   __restrict__ input_ids,     // [16384]
    float*       __restrict__ out)           // [16384][1024]
{
    __shared__ int   ids_lds[TOK_PER_BLOCK];
    __shared__ int   codes_lds[2][CHUNK * BLKS_PER_PART];  // 2 x 256 ints
    __shared__ float c_lds[N_CENTROIDS * 9];               // stride-9 padded

    const int tid  = threadIdx.x;
    const int part = blockIdx.x & (N_PARTS - 1);
    const int TB   = (blockIdx.x >> 3) * TOK_PER_BLOCK;

    // --- stage centroids: coalesced f32x4 reads -> stride-9 LDS ---
    {
        const f32x4* __restrict__ cg4 = reinterpret_cast<const f32x4*>(centroids);
        #pragma unroll
        for (int k = 0; k < 2; ++k) {
            const int i = tid + 256 * k;        // float4 index 0..511
            const f32x4 v = cg4[i];
            float* dst = &c_lds[(i >> 1) * 9 + (i & 1) * 4];
            dst[0] = v.x; dst[1] = v.y; dst[2] = v.z; dst[3] = v.w;
        }
    }
    // --- stage ids (coalesced) ---
    if (tid < TOK_PER_BLOCK)
        ids_lds[tid] = input_ids[TB + tid];
    __syncthreads();

    // Prefetch mapping: thread -> (token-in-chunk, blk16) pair.
    const int tokp = tid >> 4;   // 0..15
    const int blkp = tid & 15;   // 0..15
    const int* __restrict__ arow =
        assignments + (size_t)(part * BLKS_PER_PART + blkp) * NUM_EMBEDDINGS;

    int creg = arow[ids_lds[tokp]];   // chunk 0 prefetch (in flight)

    // Store mapping.
    const int f4    = tid & 31;   // float4 index in token's part-slice
    const int t2    = tid >> 5;   // 0..7
    const int blk16 = f4 >> 1;
    const int half  = f4 & 1;
    f32x4* __restrict__ o4 = reinterpret_cast<f32x4*>(out) + part * 32 + f4;

    #pragma unroll
    for (int i = 0; i < 4; ++i) {
        codes_lds[i & 1][tid] = creg;          // waits only the chunk-i load
        __syncthreads();

        if (i < 3)
            creg = arow[ids_lds[CHUNK * (i + 1) + tokp]];  // prefetch i+1

        #pragma unroll
        for (int s = 0; s < 2; ++s) {
            const int tok  = t2 + 8 * s;                       // 0..15
            const int code = codes_lds[i & 1][tok * BLKS_PER_PART + blk16];
            const float* __restrict__ cr = &c_lds[code * 9 + half * 4];
            f32x4 v;
            v.x = cr[0]; v.y = cr[1]; v.z = cr[2]; v.w = cr[3];
            __builtin_nontemporal_store(
                v, o4 + (size_t)(TB + CHUNK * i + tok) * (EMBEDDING_DIM / 4));
        }
        __syncthreads();
    }
}

extern "C" void kernel_launch(void* const* d_in, const int* in_sizes, int n_in,
                              void* d_out, int out_size, void* d_ws, size_t ws_size,
                              hipStream_t stream) {
    const float* centroids   = (const float*)d_in[0];
    const int*   assignments = (const int*)d_in[1];
    const int*   input_ids   = (const int*)d_in[2];
    float*       out         = (float*)d_out;

    dim3 grid((N_TOKENS / TOK_PER_BLOCK) * N_PARTS);  // 256 * 8 = 2048
    dim3 block(256);
    pq_embed_pipe_kernel<<<grid, block, 0, stream>>>(centroids, assignments, input_ids, out);
}